// Round 8
// baseline (442.710 us; speedup 1.0000x reference)
//
#include <hip/hip_runtime.h>
#include <hip/hip_cooperative_groups.h>
#include <cstdint>
#include <cstddef>

namespace cg = cooperative_groups;

#define B_   4
#define T_   2048
#define D_   1024
#define H_   8
#define DK_  64
#define HD_  512      // H*DK
#define CH_  64       // chunk length
#define NC_  32       // T_/CH_
#define EPS_ 1e-6f

typedef __attribute__((ext_vector_type(4))) float f32x4;
typedef __attribute__((ext_vector_type(8))) short s16x8;

__device__ __forceinline__ unsigned short f2bf(float f) {
    unsigned int x = __float_as_uint(f);
    unsigned int r = (x + 0x7FFFu + ((x >> 16) & 1u)) >> 16;
    return (unsigned short)r;
}
__device__ __forceinline__ float bf2f(unsigned short u) {
    return __uint_as_float(((unsigned int)u) << 16);
}
// async global->LDS, 16B per lane; LDS dest = wave-uniform base + lane*16
__device__ __forceinline__ void gl_lds16(const unsigned short* g, unsigned short* l) {
    __builtin_amdgcn_global_load_lds(
        (const __attribute__((address_space(1))) unsigned int*)g,
        (__attribute__((address_space(3))) unsigned int*)l, 16, 0, 0);
}

// ---------------- K0: fused fp32 -> bf16 convert for all six tensors ----------------
__global__ __launch_bounds__(256) void k_cvt_all(
    const float* __restrict__ x,
    const float* __restrict__ wq, const float* __restrict__ wk,
    const float* __restrict__ wv, const float* __restrict__ wgw,
    const float* __restrict__ wo,
    unsigned short* __restrict__ xb,
    unsigned short* __restrict__ wqb, unsigned short* __restrict__ wkb,
    unsigned short* __restrict__ wvb, unsigned short* __restrict__ wgb,
    unsigned short* __restrict__ wob)
{
    int bid = blockIdx.x;
    const float* src; unsigned short* dst; int idx;
    if (bid < 8192) {
        src = x; dst = xb; idx = bid * 256 + threadIdx.x;
    } else {
        int r = bid - 8192;
        int w = r >> 9;
        idx = (r & 511) * 256 + threadIdx.x;
        switch (w) {
            case 0:  src = wq;  dst = wqb; break;
            case 1:  src = wk;  dst = wkb; break;
            case 2:  src = wv;  dst = wvb; break;
            case 3:  src = wgw; dst = wgb; break;
            default: src = wo;  dst = wob; break;
        }
    }
    float4 v = ((const float4*)src)[idx];
    ushort4 o;
    o.x = f2bf(v.x); o.y = f2bf(v.y); o.z = f2bf(v.z); o.w = f2bf(v.w);
    ((ushort4*)dst)[idx] = o;
}

// ---------------- K1: fused QKVG GEMM, 256x256 tile, counted-vmcnt pipeline (best-wall form) ----------------
__global__ __launch_bounds__(512, 2) void k_gemm_qkvg(
    const unsigned short* __restrict__ xb,
    const unsigned short* __restrict__ wqb, const unsigned short* __restrict__ wkb,
    const unsigned short* __restrict__ wvb, const unsigned short* __restrict__ wgb,
    const float* __restrict__ bias,
    unsigned short* __restrict__ qo, unsigned short* __restrict__ ko,
    unsigned short* __restrict__ vo, unsigned short* __restrict__ go)
{
    __shared__ unsigned short As[2][256 * 64];   // 64KB
    __shared__ unsigned short Bs[2][256 * 64];   // 64KB
    const int tid = threadIdx.x;
    const int id  = blockIdx.x;                  // 0..255
    const int xcd = id & 7, per = id >> 3;       // per 0..31
    const int mtile = xcd * 4 + (per & 3);       // 0..31
    const int ntile = per >> 2;                  // 0..7
    const int which = ntile >> 1;                // 0=Q 1=K 2=V 3=G
    const int nb    = ntile & 1;
    const int m0    = mtile * 256;
    const int n0    = nb * 256;
    const unsigned short* Wp = (which == 0) ? wqb : (which == 1) ? wkb : (which == 2) ? wvb : wgb;
    unsigned short* Op       = (which == 0) ? qo  : (which == 1) ? ko  : (which == 2) ? vo  : go;
    const int K = D_;
    const int NIT = K / 64;                      // 16

    const int lane = tid & 63, wave = tid >> 6;  // wave 0..7
    const int wm = (wave >> 2) * 128, wn = (wave & 3) * 64;
    const int r16 = lane & 15, quad = lane >> 4;
    const int lrow = lane >> 3, lseg = lane & 7;
    const int sseg = lseg ^ lrow;                // XOR swizzle
    const int rx   = r16 & 7;

    f32x4 acc[8][4];
    #pragma unroll
    for (int a = 0; a < 8; a++)
        #pragma unroll
        for (int b = 0; b < 4; b++) acc[a][b] = 0.0f;

    auto stage = [&](int buf, int ko_) {
        #pragma unroll
        for (int i = 0; i < 4; i++) {
            int chunk = wave * 4 + i;            // 0..31, wave-uniform
            int row = chunk * 8 + lrow;          // 0..255
            gl_lds16(xb + (size_t)(m0 + row) * K + ko_ + sseg * 8, &As[buf][chunk * 512]);
            gl_lds16(Wp + (size_t)(n0 + row) * K + ko_ + sseg * 8, &Bs[buf][chunk * 512]);
        }
    };

    stage(0, 0);
    for (int it = 0; it < NIT; ++it) {
        if (it + 1 < NIT) {
            stage((it + 1) & 1, (it + 1) * 64);
            asm volatile("s_waitcnt vmcnt(8)" ::: "memory");
        } else {
            asm volatile("s_waitcnt vmcnt(0)" ::: "memory");
        }
        __builtin_amdgcn_s_barrier();
        const int buf = it & 1;
        #pragma unroll
        for (int kk = 0; kk < 64; kk += 32) {
            const int gb_ = kk >> 3;
            s16x8 af[8], bf[4];
            #pragma unroll
            for (int mt = 0; mt < 8; mt++)
                af[mt] = *(const s16x8*)&As[buf][(wm + mt * 16 + r16) * 64 + (((gb_ + quad) ^ rx) << 3)];
            #pragma unroll
            for (int nt = 0; nt < 4; nt++)
                bf[nt] = *(const s16x8*)&Bs[buf][(wn + nt * 16 + r16) * 64 + (((gb_ + quad) ^ rx) << 3)];
            #pragma unroll
            for (int mt = 0; mt < 8; mt++)
                #pragma unroll
                for (int nt = 0; nt < 4; nt++)
                    acc[mt][nt] = __builtin_amdgcn_mfma_f32_16x16x32_bf16(af[mt], bf[nt], acc[mt][nt], 0, 0, 0);
        }
        __builtin_amdgcn_s_barrier();
    }
    #pragma unroll
    for (int mt = 0; mt < 8; mt++) {
        #pragma unroll
        for (int nt = 0; nt < 4; nt++) {
            int col = n0 + wn + nt * 16 + r16;
            float bv = (which == 3) ? bias[col] : 0.0f;
            #pragma unroll
            for (int r = 0; r < 4; r++) {
                int row = m0 + wm + mt * 16 + quad * 4 + r;
                float v = acc[mt][nt][r];
                if (which <= 1)      v = (v > 0.0f) ? v + 1.0f : __builtin_expf(v);     // phi = elu+1
                else if (which == 3) v = 1.0f / (1.0f + __builtin_expf(-(v + bv)));     // sigmoid gate
                Op[(size_t)row * HD_ + col] = f2bf(v);
            }
        }
    }
}

// ---------------- K5: output GEMM: Y = OG @ W_O^T (fp32 out), 256x128, counted vmcnt ----------------
__global__ __launch_bounds__(512, 2) void k_gemm_out(
    const unsigned short* __restrict__ ogb, const unsigned short* __restrict__ wob,
    float* __restrict__ y)
{
    __shared__ unsigned short As[2][256 * 64];   // 64KB
    __shared__ unsigned short Bs[2][128 * 64];   // 32KB
    const int tid = threadIdx.x;
    const int id  = blockIdx.x;                  // 0..255
    const int xcd = id & 7, per = id >> 3;
    const int m0 = (xcd * 4 + (per & 3)) * 256;
    const int n0 = (per >> 2) * 128;
    const int K = HD_;                           // 512
    const int NIT = K / 64;                      // 8

    const int lane = tid & 63, wave = tid >> 6;  // 8 waves, 4M x 2N
    const int wm = (wave >> 1) * 64, wn = (wave & 1) * 64;
    const int r16 = lane & 15, quad = lane >> 4;
    const int lrow = lane >> 3, lseg = lane & 7;
    const int sseg = lseg ^ lrow;
    const int rx   = r16 & 7;

    f32x4 acc[4][4];
    #pragma unroll
    for (int a = 0; a < 4; a++)
        #pragma unroll
        for (int b = 0; b < 4; b++) acc[a][b] = 0.0f;

    auto stage = [&](int buf, int ko_) {
        #pragma unroll
        for (int i = 0; i < 4; i++) {
            int chunk = wave * 4 + i;
            int row = chunk * 8 + lrow;
            gl_lds16(ogb + (size_t)(m0 + row) * K + ko_ + sseg * 8, &As[buf][chunk * 512]);
        }
        #pragma unroll
        for (int i = 0; i < 2; i++) {
            int chunk = wave * 2 + i;
            int row = chunk * 8 + lrow;
            gl_lds16(wob + (size_t)(n0 + row) * K + ko_ + sseg * 8, &Bs[buf][chunk * 512]);
        }
    };

    stage(0, 0);
    for (int it = 0; it < NIT; ++it) {
        if (it + 1 < NIT) {
            stage((it + 1) & 1, (it + 1) * 64);
            asm volatile("s_waitcnt vmcnt(6)" ::: "memory");
        } else {
            asm volatile("s_waitcnt vmcnt(0)" ::: "memory");
        }
        __builtin_amdgcn_s_barrier();
        const int buf = it & 1;
        #pragma unroll
        for (int kk = 0; kk < 64; kk += 32) {
            const int gb_ = kk >> 3;
            s16x8 af[4], bf[4];
            #pragma unroll
            for (int mt = 0; mt < 4; mt++)
                af[mt] = *(const s16x8*)&As[buf][(wm + mt * 16 + r16) * 64 + (((gb_ + quad) ^ rx) << 3)];
            #pragma unroll
            for (int nt = 0; nt < 4; nt++)
                bf[nt] = *(const s16x8*)&Bs[buf][(wn + nt * 16 + r16) * 64 + (((gb_ + quad) ^ rx) << 3)];
            #pragma unroll
            for (int mt = 0; mt < 4; mt++)
                #pragma unroll
                for (int nt = 0; nt < 4; nt++)
                    acc[mt][nt] = __builtin_amdgcn_mfma_f32_16x16x32_bf16(af[mt], bf[nt], acc[mt][nt], 0, 0, 0);
        }
        __builtin_amdgcn_s_barrier();
    }
    #pragma unroll
    for (int mt = 0; mt < 4; mt++)
        #pragma unroll
        for (int nt = 0; nt < 4; nt++) {
            int col = n0 + wn + nt * 16 + r16;
            #pragma unroll
            for (int r = 0; r < 4; r++) {
                int row = m0 + wm + mt * 16 + quad * 4 + r;
                y[(size_t)row * D_ + col] = acc[mt][nt][r];
            }
        }
}

// ---------------- K2+K3+K4 merged: cooperative chunk pipeline ----------------
// 512 blocks x 256 threads, 2 chunks per block (bc = blockIdx, blockIdx+512; same h).
// Phase A = per-chunk decayed sums (MFMA, r7-K2 body); grid sync;
// Phase B = exclusive scan (r7-K3 logic, remapped to 131072 threads); grid sync;
// Phase C = per-chunk outputs (MFMA, r7-K4 body).
// LDS 56KB -> exactly 2 blocks/CU co-resident (co-residency required by grid.sync).
__global__ __launch_bounds__(256, 2) void k_chunk_all(
    const unsigned short* __restrict__ Qb, const unsigned short* __restrict__ Kb,
    const unsigned short* __restrict__ Vb, const unsigned short* __restrict__ Gb,
    float* __restrict__ Ssum, float* __restrict__ zsum,
    unsigned short* __restrict__ OGb, const float* __restrict__ decay_log)
{
    __shared__ unsigned short kt[64 * 72];   // khat^T [d][l], decay folded (phase A)
    __shared__ unsigned short vt[64 * 72];   // v^T [d][l] (A and C, restaged)
    __shared__ unsigned short ql[64 * 72];   // q rows (C)
    __shared__ unsigned short kl[64 * 72];   // k rows (C)
    __shared__ unsigned short sT[64 * 72];   // S_prev^T bf16 (C)
    __shared__ unsigned short pl[64 * 72];   // P [i][l] bf16 (C)
    __shared__ float den_l[64];
    __shared__ float zp[64];
    __shared__ float gpow[CH_ + 1];

    const int tid = threadIdx.x;
    const int lane = tid & 63, wave = tid >> 6;
    const int r16 = lane & 15, quad = lane >> 4;
    cg::grid_group grid = cg::this_grid();

    // ================= PHASE A: per-chunk decayed sums =================
    for (int rep = 0; rep < 2; ++rep) {
        if (rep) __syncthreads();
        const int bc = blockIdx.x + rep * 512;
        const int c   = bc & (NC_ - 1);
        const int bh  = bc >> 5;
        const int h   = bh & (H_ - 1);
        const int b   = bh >> 3;
        const float g  = 1.0f / (1.0f + __builtin_expf(-decay_log[h]));
        const float lg = __builtin_log2f(g);
        const int t0 = c * CH_;

        #pragma unroll
        for (int e = 0; e < 2; e++) {
            int lid = e * 256 + tid;
            int l = lid >> 3, d0 = (lid & 7) * 8;
            float w = __builtin_exp2f((float)(CH_ - 1 - l) * lg);
            size_t gidx = (size_t)(b * T_ + t0 + l) * HD_ + h * DK_ + d0;
            uint4 kraw = *(const uint4*)(Kb + gidx);
            uint4 vraw = *(const uint4*)(Vb + gidx);
            const unsigned short* kp = (const unsigned short*)&kraw;
            const unsigned short* vp = (const unsigned short*)&vraw;
            #pragma unroll
            for (int j = 0; j < 8; j++) {
                kt[(d0 + j) * 72 + l] = f2bf(bf2f(kp[j]) * w);
                vt[(d0 + j) * 72 + l] = vp[j];
            }
        }
        __syncthreads();

        size_t base = (size_t)bc * (DK_ * DK_);
        #pragma unroll
        for (int it = 0; it < 4; it++) {
            f32x4 sacc = 0.0f;
            #pragma unroll
            for (int ks = 0; ks < 2; ks++) {
                s16x8 af  = *(const s16x8*)&vt[(16 * wave + r16) * 72 + ks * 32 + quad * 8];
                s16x8 bf_ = *(const s16x8*)&kt[(16 * it   + r16) * 72 + ks * 32 + quad * 8];
                sacc = __builtin_amdgcn_mfma_f32_16x16x32_bf16(af, bf_, sacc, 0, 0, 0);
            }
            #pragma unroll
            for (int rr = 0; rr < 4; rr++)
                Ssum[base + (size_t)(16 * wave + quad * 4 + rr) * DK_ + 16 * it + r16] = sacc[rr];
        }
        if (tid < DK_) {
            float s = 0.0f;
            #pragma unroll
            for (int l8 = 0; l8 < 8; l8++) {
                uint4 kk = *(const uint4*)&kt[tid * 72 + l8 * 8];
                const unsigned short* kp = (const unsigned short*)&kk;
                #pragma unroll
                for (int e = 0; e < 8; e++) s += bf2f(kp[e]);
            }
            zsum[(size_t)bc * DK_ + tid] = s;
        }
    }

    __threadfence();
    grid.sync();

    // ================= PHASE B: exclusive cross-chunk scan =================
    {
        int id = blockIdx.x * 256 + tid;          // 0..131071
        int bh = id >> 12;                        // 0..31
        int elem = id & 4095;
        const int h = bh & (H_ - 1);
        const float g  = 1.0f / (1.0f + __builtin_expf(-decay_log[h]));
        const float gC = __builtin_exp2f((float)CH_ * __builtin_log2f(g));
        float s = 0.0f;
        for (int c = 0; c < NC_; c++) {
            size_t idx = ((size_t)(bh * NC_ + c)) * 4096 + elem;
            float v = Ssum[idx];
            Ssum[idx] = s;
            s = gC * s + v;
        }
        if (id < 32 * DK_) {                      // z-scan: 2048 threads
            int zbh = id >> 6, zelem = id & 63;
            const int zh = zbh & (H_ - 1);
            const float zg  = 1.0f / (1.0f + __builtin_expf(-decay_log[zh]));
            const float zgC = __builtin_exp2f((float)CH_ * __builtin_log2f(zg));
            float z = 0.0f;
            for (int c = 0; c < NC_; c++) {
                size_t idx = ((size_t)(zbh * NC_ + c)) * DK_ + zelem;
                float v = zsum[idx];
                zsum[idx] = z;
                z = zgC * z + v;
            }
        }
    }

    __threadfence();
    grid.sync();

    // ================= PHASE C: per-chunk outputs =================
    for (int rep = 0; rep < 2; ++rep) {
        __syncthreads();
        const int bc = blockIdx.x + rep * 512;
        const int c   = bc & (NC_ - 1);
        const int bh  = bc >> 5;
        const int h   = bh & (H_ - 1);
        const int b   = bh >> 3;
        const float g  = 1.0f / (1.0f + __builtin_expf(-decay_log[h]));
        const float lg = __builtin_log2f(g);
        const int t0 = c * CH_;

        if (tid <= CH_) gpow[tid] = __builtin_exp2f((float)tid * lg);
        if (tid < DK_)  zp[tid] = zsum[(size_t)bc * DK_ + tid];

        #pragma unroll
        for (int e = 0; e < 2; e++) {
            int lid = e * 256 + tid;
            int l = lid >> 3, d0 = (lid & 7) * 8;
            size_t gidx = (size_t)(b * T_ + t0 + l) * HD_ + h * DK_ + d0;
            uint4 qraw = *(const uint4*)(Qb + gidx);
            uint4 kraw = *(const uint4*)(Kb + gidx);
            uint4 vraw = *(const uint4*)(Vb + gidx);
            *(uint4*)&ql[l * 72 + d0] = qraw;
            *(uint4*)&kl[l * 72 + d0] = kraw;
            const unsigned short* vp = (const unsigned short*)&vraw;
            #pragma unroll
            for (int j = 0; j < 8; j++) vt[(d0 + j) * 72 + l] = vp[j];
        }
        {   // stage S_prev^T -> bf16
            int j = tid >> 2, seg = tid & 3;
            const float4* src = (const float4*)&Ssum[(size_t)bc * 4096 + (size_t)j * 64 + seg * 16];
            #pragma unroll
            for (int e = 0; e < 4; e++) {
                float4 a4 = src[e];
                ushort4 o;
                o.x = f2bf(a4.x); o.y = f2bf(a4.y); o.z = f2bf(a4.z); o.w = f2bf(a4.w);
                *(ushort4*)&sT[j * 72 + seg * 16 + e * 4] = o;
            }
        }
        __syncthreads();

        const int ibase = 16 * wave;
        s16x8 aq[2];
        #pragma unroll
        for (int ks = 0; ks < 2; ks++)
            aq[ks] = *(const s16x8*)&ql[(ibase + r16) * 72 + ks * 32 + quad * 8];

        // SC = Q K^T
        f32x4 sc4[4];
        #pragma unroll
        for (int lt = 0; lt < 4; lt++) {
            f32x4 s = 0.0f;
            #pragma unroll
            for (int ks = 0; ks < 2; ks++) {
                s16x8 bf_ = *(const s16x8*)&kl[(16 * lt + r16) * 72 + ks * 32 + quad * 8];
                s = __builtin_amdgcn_mfma_f32_16x16x32_bf16(aq[ks], bf_, s, 0, 0, 0);
            }
            sc4[lt] = s;
        }
        // mask + decay -> P + intra row-sums
        float rs[4] = {0.0f, 0.0f, 0.0f, 0.0f};
        #pragma unroll
        for (int lt = 0; lt < 4; lt++) {
            int l = 16 * lt + r16;
            #pragma unroll
            for (int rr = 0; rr < 4; rr++) {
                int i = ibase + quad * 4 + rr;
                float val = (l <= i) ? sc4[lt][rr] * gpow[i - l] : 0.0f;
                unsigned short pb = f2bf(val);
                pl[i * 72 + l] = pb;
                rs[rr] += bf2f(pb);
            }
        }
        #pragma unroll
        for (int rr = 0; rr < 4; rr++) {
            float v_ = rs[rr];
            v_ += __shfl_xor(v_, 1);
            v_ += __shfl_xor(v_, 2);
            v_ += __shfl_xor(v_, 4);
            v_ += __shfl_xor(v_, 8);
            if (r16 == 0) den_l[ibase + quad * 4 + rr] = v_;
        }
        // carried = Q * S_prev^T, scaled
        f32x4 og[4];
        #pragma unroll
        for (int jt = 0; jt < 4; jt++) {
            f32x4 o = 0.0f;
            #pragma unroll
            for (int ks = 0; ks < 2; ks++) {
                s16x8 bf_ = *(const s16x8*)&sT[(16 * jt + r16) * 72 + ks * 32 + quad * 8];
                o = __builtin_amdgcn_mfma_f32_16x16x32_bf16(aq[ks], bf_, o, 0, 0, 0);
            }
            #pragma unroll
            for (int rr = 0; rr < 4; rr++)
                o[rr] *= gpow[ibase + quad * 4 + rr + 1];
            og[jt] = o;
        }
        __syncthreads();

        // PV: og += P * v^T
        #pragma unroll
        for (int jt = 0; jt < 4; jt++) {
            #pragma unroll
            for (int ks = 0; ks < 2; ks++) {
                s16x8 ap  = *(const s16x8*)&pl[(ibase + r16) * 72 + ks * 32 + quad * 8];
                s16x8 bf_ = *(const s16x8*)&vt[(16 * jt + r16) * 72 + ks * 32 + quad * 8];
                og[jt] = __builtin_amdgcn_mfma_f32_16x16x32_bf16(ap, bf_, og[jt], 0, 0, 0);
            }
        }
        // denominator finalize
        if (tid < DK_) {
            float dp = 0.0f;
            #pragma unroll
            for (int d8 = 0; d8 < 8; d8++) {
                uint4 qq = *(const uint4*)&ql[tid * 72 + d8 * 8];
                const unsigned short* qp = (const unsigned short*)&qq;
                #pragma unroll
                for (int e = 0; e < 8; e++) dp += bf2f(qp[e]) * zp[d8 * 8 + e];
            }
            den_l[tid] += gpow[tid + 1] * dp + EPS_;
        }
        __syncthreads();

        // epilogue
        #pragma unroll
        for (int jt = 0; jt < 4; jt++) {
            int j = 16 * jt + r16;
            #pragma unroll
            for (int rr = 0; rr < 4; rr++) {
                int i = ibase + quad * 4 + rr;
                float rcp = 1.0f / den_l[i];
                size_t ga = (size_t)(b * T_ + t0 + i) * HD_ + h * DK_ + j;
                float gate = bf2f(Gb[ga]);
                OGb[ga] = f2bf(og[jt][rr] * rcp * gate);
            }
        }
    }
}

// ---------------- host ----------------
extern "C" void kernel_launch(void* const* d_in, const int* in_sizes, int n_in,
                              void* d_out, int out_size, void* d_ws, size_t ws_size,
                              hipStream_t stream)
{
    (void)in_sizes; (void)n_in; (void)out_size; (void)ws_size;
    const float* x         = (const float*)d_in[0];
    const float* W_Q       = (const float*)d_in[1];
    const float* W_K       = (const float*)d_in[2];
    const float* W_V       = (const float*)d_in[3];
    const float* W_gw      = (const float*)d_in[4];
    const float* W_gb      = (const float*)d_in[5];
    const float* W_O       = (const float*)d_in[6];
    const float* decay_log = (const float*)d_in[7];
    float* y = (float*)d_out;

    char* ws = (char*)d_ws;
    size_t off = 0;
    auto alloc = [&](size_t bytes) { void* p = ws + off; off += (bytes + 255) & ~(size_t)255; return p; };
    unsigned short* xb   = (unsigned short*)alloc((size_t)B_ * T_ * D_ * 2);
    unsigned short* wqb  = (unsigned short*)alloc((size_t)HD_ * D_ * 2);
    unsigned short* wkb  = (unsigned short*)alloc((size_t)HD_ * D_ * 2);
    unsigned short* wvb  = (unsigned short*)alloc((size_t)HD_ * D_ * 2);
    unsigned short* wgb  = (unsigned short*)alloc((size_t)HD_ * D_ * 2);
    unsigned short* wob  = (unsigned short*)alloc((size_t)D_ * HD_ * 2);
    unsigned short* qb   = (unsigned short*)alloc((size_t)B_ * T_ * HD_ * 2);
    unsigned short* kb   = (unsigned short*)alloc((size_t)B_ * T_ * HD_ * 2);
    unsigned short* vb   = (unsigned short*)alloc((size_t)B_ * T_ * HD_ * 2);
    unsigned short* gb   = (unsigned short*)alloc((size_t)B_ * T_ * HD_ * 2);
    unsigned short* ogb  = (unsigned short*)alloc((size_t)B_ * T_ * HD_ * 2);
    float* Ssum = (float*)alloc((size_t)B_ * H_ * NC_ * DK_ * DK_ * 4);
    float* zsum = (float*)alloc((size_t)B_ * H_ * NC_ * DK_ * 4);

    k_cvt_all<<<8192 + 5 * 512, 256, 0, stream>>>(x, W_Q, W_K, W_V, W_gw, W_O,
                                                  xb, wqb, wkb, wvb, wgb, wob);
    k_gemm_qkvg<<<256, 512, 0, stream>>>(xb, wqb, wkb, wvb, wgb, W_gb, qb, kb, vb, gb);

    {
        void* args[] = { (void*)&qb, (void*)&kb, (void*)&vb, (void*)&gb,
                         (void*)&Ssum, (void*)&zsum, (void*)&ogb, (void*)&decay_log };
        hipLaunchCooperativeKernel((const void*)k_chunk_all, dim3(512), dim3(256),
                                   args, 0, stream);
    }

    k_gemm_out<<<256, 512, 0, stream>>>(ogb, wob, y);
}

// Round 9
// 197.929 us; speedup vs baseline: 2.2367x; 2.2367x over previous
//
#include <hip/hip_runtime.h>
#include <cstdint>
#include <cstddef>

#define B_   4
#define T_   2048
#define D_   1024
#define H_   8
#define DK_  64
#define HD_  512      // H*DK
#define CH_  64       // chunk length
#define NC_  32       // T_/CH_
#define EPS_ 1e-6f

typedef __attribute__((ext_vector_type(4))) float f32x4;
typedef __attribute__((ext_vector_type(8))) short s16x8;

__device__ __forceinline__ unsigned short f2bf(float f) {
    unsigned int x = __float_as_uint(f);
    unsigned int r = (x + 0x7FFFu + ((x >> 16) & 1u)) >> 16;
    return (unsigned short)r;
}
__device__ __forceinline__ float bf2f(unsigned short u) {
    return __uint_as_float(((unsigned int)u) << 16);
}
// async global->LDS, 16B per lane; LDS dest = wave-uniform base + lane*16
__device__ __forceinline__ void gl_lds16(const unsigned short* g, unsigned short* l) {
    __builtin_amdgcn_global_load_lds(
        (const __attribute__((address_space(1))) unsigned int*)g,
        (__attribute__((address_space(3))) unsigned int*)l, 16, 0, 0);
}

// ---------------- K0: fused fp32 -> bf16 convert for all six tensors ----------------
__global__ __launch_bounds__(256) void k_cvt_all(
    const float* __restrict__ x,
    const float* __restrict__ wq, const float* __restrict__ wk,
    const float* __restrict__ wv, const float* __restrict__ wgw,
    const float* __restrict__ wo,
    unsigned short* __restrict__ xb,
    unsigned short* __restrict__ wqb, unsigned short* __restrict__ wkb,
    unsigned short* __restrict__ wvb, unsigned short* __restrict__ wgb,
    unsigned short* __restrict__ wob)
{
    int bid = blockIdx.x;
    const float* src; unsigned short* dst; int idx;
    if (bid < 8192) {
        src = x; dst = xb; idx = bid * 256 + threadIdx.x;
    } else {
        int r = bid - 8192;
        int w = r >> 9;
        idx = (r & 511) * 256 + threadIdx.x;
        switch (w) {
            case 0:  src = wq;  dst = wqb; break;
            case 1:  src = wk;  dst = wkb; break;
            case 2:  src = wv;  dst = wvb; break;
            case 3:  src = wgw; dst = wgb; break;
            default: src = wo;  dst = wob; break;
        }
    }
    float4 v = ((const float4*)src)[idx];
    ushort4 o;
    o.x = f2bf(v.x); o.y = f2bf(v.y); o.z = f2bf(v.z); o.w = f2bf(v.w);
    ((ushort4*)dst)[idx] = o;
}

// ---------------- K1: fused QKVG GEMM, 256x256 tile, counted-vmcnt pipeline (best-wall form) ----------------
__global__ __launch_bounds__(512, 2) void k_gemm_qkvg(
    const unsigned short* __restrict__ xb,
    const unsigned short* __restrict__ wqb, const unsigned short* __restrict__ wkb,
    const unsigned short* __restrict__ wvb, const unsigned short* __restrict__ wgb,
    const float* __restrict__ bias,
    unsigned short* __restrict__ qo, unsigned short* __restrict__ ko,
    unsigned short* __restrict__ vo, unsigned short* __restrict__ go)
{
    __shared__ unsigned short As[2][256 * 64];   // 64KB
    __shared__ unsigned short Bs[2][256 * 64];   // 64KB
    const int tid = threadIdx.x;
    const int id  = blockIdx.x;                  // 0..255
    const int xcd = id & 7, per = id >> 3;       // per 0..31
    const int mtile = xcd * 4 + (per & 3);       // 0..31
    const int ntile = per >> 2;                  // 0..7
    const int which = ntile >> 1;                // 0=Q 1=K 2=V 3=G
    const int nb    = ntile & 1;
    const int m0    = mtile * 256;
    const int n0    = nb * 256;
    const unsigned short* Wp = (which == 0) ? wqb : (which == 1) ? wkb : (which == 2) ? wvb : wgb;
    unsigned short* Op       = (which == 0) ? qo  : (which == 1) ? ko  : (which == 2) ? vo  : go;
    const int K = D_;
    const int NIT = K / 64;                      // 16

    const int lane = tid & 63, wave = tid >> 6;  // wave 0..7
    const int wm = (wave >> 2) * 128, wn = (wave & 3) * 64;
    const int r16 = lane & 15, quad = lane >> 4;
    const int lrow = lane >> 3, lseg = lane & 7;
    const int sseg = lseg ^ lrow;                // XOR swizzle
    const int rx   = r16 & 7;

    f32x4 acc[8][4];
    #pragma unroll
    for (int a = 0; a < 8; a++)
        #pragma unroll
        for (int b = 0; b < 4; b++) acc[a][b] = 0.0f;

    auto stage = [&](int buf, int ko_) {
        #pragma unroll
        for (int i = 0; i < 4; i++) {
            int chunk = wave * 4 + i;            // 0..31, wave-uniform
            int row = chunk * 8 + lrow;          // 0..255
            gl_lds16(xb + (size_t)(m0 + row) * K + ko_ + sseg * 8, &As[buf][chunk * 512]);
            gl_lds16(Wp + (size_t)(n0 + row) * K + ko_ + sseg * 8, &Bs[buf][chunk * 512]);
        }
    };

    stage(0, 0);
    for (int it = 0; it < NIT; ++it) {
        if (it + 1 < NIT) {
            stage((it + 1) & 1, (it + 1) * 64);
            asm volatile("s_waitcnt vmcnt(8)" ::: "memory");
        } else {
            asm volatile("s_waitcnt vmcnt(0)" ::: "memory");
        }
        __builtin_amdgcn_s_barrier();
        const int buf = it & 1;
        #pragma unroll
        for (int kk = 0; kk < 64; kk += 32) {
            const int gb_ = kk >> 3;
            s16x8 af[8], bf[4];
            #pragma unroll
            for (int mt = 0; mt < 8; mt++)
                af[mt] = *(const s16x8*)&As[buf][(wm + mt * 16 + r16) * 64 + (((gb_ + quad) ^ rx) << 3)];
            #pragma unroll
            for (int nt = 0; nt < 4; nt++)
                bf[nt] = *(const s16x8*)&Bs[buf][(wn + nt * 16 + r16) * 64 + (((gb_ + quad) ^ rx) << 3)];
            #pragma unroll
            for (int mt = 0; mt < 8; mt++)
                #pragma unroll
                for (int nt = 0; nt < 4; nt++)
                    acc[mt][nt] = __builtin_amdgcn_mfma_f32_16x16x32_bf16(af[mt], bf[nt], acc[mt][nt], 0, 0, 0);
        }
        __builtin_amdgcn_s_barrier();
    }
    #pragma unroll
    for (int mt = 0; mt < 8; mt++) {
        #pragma unroll
        for (int nt = 0; nt < 4; nt++) {
            int col = n0 + wn + nt * 16 + r16;
            float bv = (which == 3) ? bias[col] : 0.0f;
            #pragma unroll
            for (int r = 0; r < 4; r++) {
                int row = m0 + wm + mt * 16 + quad * 4 + r;
                float v = acc[mt][nt][r];
                if (which <= 1)      v = (v > 0.0f) ? v + 1.0f : __builtin_expf(v);     // phi = elu+1
                else if (which == 3) v = 1.0f / (1.0f + __builtin_expf(-(v + bv)));     // sigmoid gate
                Op[(size_t)row * HD_ + col] = f2bf(v);
            }
        }
    }
}

// ---------------- K5: output GEMM: Y = OG @ W_O^T (fp32 out), 256x128, counted vmcnt ----------------
__global__ __launch_bounds__(512, 2) void k_gemm_out(
    const unsigned short* __restrict__ ogb, const unsigned short* __restrict__ wob,
    float* __restrict__ y)
{
    __shared__ unsigned short As[2][256 * 64];   // 64KB
    __shared__ unsigned short Bs[2][128 * 64];   // 32KB
    const int tid = threadIdx.x;
    const int id  = blockIdx.x;                  // 0..255
    const int xcd = id & 7, per = id >> 3;
    const int m0 = (xcd * 4 + (per & 3)) * 256;
    const int n0 = (per >> 2) * 128;
    const int K = HD_;                           // 512
    const int NIT = K / 64;                      // 8

    const int lane = tid & 63, wave = tid >> 6;  // 8 waves, 4M x 2N
    const int wm = (wave >> 1) * 64, wn = (wave & 1) * 64;
    const int r16 = lane & 15, quad = lane >> 4;
    const int lrow = lane >> 3, lseg = lane & 7;
    const int sseg = lseg ^ lrow;
    const int rx   = r16 & 7;

    f32x4 acc[4][4];
    #pragma unroll
    for (int a = 0; a < 4; a++)
        #pragma unroll
        for (int b = 0; b < 4; b++) acc[a][b] = 0.0f;

    auto stage = [&](int buf, int ko_) {
        #pragma unroll
        for (int i = 0; i < 4; i++) {
            int chunk = wave * 4 + i;
            int row = chunk * 8 + lrow;
            gl_lds16(ogb + (size_t)(m0 + row) * K + ko_ + sseg * 8, &As[buf][chunk * 512]);
        }
        #pragma unroll
        for (int i = 0; i < 2; i++) {
            int chunk = wave * 2 + i;
            int row = chunk * 8 + lrow;
            gl_lds16(wob + (size_t)(n0 + row) * K + ko_ + sseg * 8, &Bs[buf][chunk * 512]);
        }
    };

    stage(0, 0);
    for (int it = 0; it < NIT; ++it) {
        if (it + 1 < NIT) {
            stage((it + 1) & 1, (it + 1) * 64);
            asm volatile("s_waitcnt vmcnt(6)" ::: "memory");
        } else {
            asm volatile("s_waitcnt vmcnt(0)" ::: "memory");
        }
        __builtin_amdgcn_s_barrier();
        const int buf = it & 1;
        #pragma unroll
        for (int kk = 0; kk < 64; kk += 32) {
            const int gb_ = kk >> 3;
            s16x8 af[4], bf[4];
            #pragma unroll
            for (int mt = 0; mt < 4; mt++)
                af[mt] = *(const s16x8*)&As[buf][(wm + mt * 16 + r16) * 64 + (((gb_ + quad) ^ rx) << 3)];
            #pragma unroll
            for (int nt = 0; nt < 4; nt++)
                bf[nt] = *(const s16x8*)&Bs[buf][(wn + nt * 16 + r16) * 64 + (((gb_ + quad) ^ rx) << 3)];
            #pragma unroll
            for (int mt = 0; mt < 4; mt++)
                #pragma unroll
                for (int nt = 0; nt < 4; nt++)
                    acc[mt][nt] = __builtin_amdgcn_mfma_f32_16x16x32_bf16(af[mt], bf[nt], acc[mt][nt], 0, 0, 0);
        }
        __builtin_amdgcn_s_barrier();
    }
    #pragma unroll
    for (int mt = 0; mt < 4; mt++)
        #pragma unroll
        for (int nt = 0; nt < 4; nt++) {
            int col = n0 + wn + nt * 16 + r16;
            #pragma unroll
            for (int r = 0; r < 4; r++) {
                int row = m0 + wm + mt * 16 + quad * 4 + r;
                y[(size_t)row * D_ + col] = acc[mt][nt][r];
            }
        }
}

// ---------------- K2: per-chunk decayed sums via MFMA (stores S^T) ----------------
__global__ __launch_bounds__(256) void k_chunk_sums(
    const unsigned short* __restrict__ Kb, const unsigned short* __restrict__ Vb,
    float* __restrict__ Ssum, float* __restrict__ zsum, const float* __restrict__ decay_log)
{
    __shared__ unsigned short kt[64 * 72];   // khat^T [d][l], decay folded, bf16
    __shared__ unsigned short vt[64 * 72];   // v^T    [d][l], bf16
    const int tid = threadIdx.x;
    const int bc  = blockIdx.x;            // bh*NC_ + c
    const int c   = bc & (NC_ - 1);
    const int bh  = bc >> 5;
    const int h   = bh & (H_ - 1);
    const int b   = bh >> 3;
    const float g  = 1.0f / (1.0f + __builtin_expf(-decay_log[h]));
    const float lg = __builtin_log2f(g);
    const int t0 = c * CH_;

    #pragma unroll
    for (int e = 0; e < 2; e++) {
        int lid = e * 256 + tid;           // 0..511 : 64 rows x 8 segs
        int l = lid >> 3, d0 = (lid & 7) * 8;
        float w = __builtin_exp2f((float)(CH_ - 1 - l) * lg);
        size_t gidx = (size_t)(b * T_ + t0 + l) * HD_ + h * DK_ + d0;
        uint4 kraw = *(const uint4*)(Kb + gidx);
        uint4 vraw = *(const uint4*)(Vb + gidx);
        const unsigned short* kp = (const unsigned short*)&kraw;
        const unsigned short* vp = (const unsigned short*)&vraw;
        #pragma unroll
        for (int j = 0; j < 8; j++) {
            kt[(d0 + j) * 72 + l] = f2bf(bf2f(kp[j]) * w);
            vt[(d0 + j) * 72 + l] = vp[j];
        }
    }
    __syncthreads();

    const int lane = tid & 63, wave = tid >> 6;
    const int r16 = lane & 15, quad = lane >> 4;
    size_t base = (size_t)bc * (DK_ * DK_);

    // wave owns j-band (16*wave .. +15); it = k-dim tile 0..3
    #pragma unroll
    for (int it = 0; it < 4; it++) {
        f32x4 sacc = 0.0f;
        #pragma unroll
        for (int ks = 0; ks < 2; ks++) {
            s16x8 af  = *(const s16x8*)&vt[(16 * wave + r16) * 72 + ks * 32 + quad * 8];
            s16x8 bf_ = *(const s16x8*)&kt[(16 * it   + r16) * 72 + ks * 32 + quad * 8];
            sacc = __builtin_amdgcn_mfma_f32_16x16x32_bf16(af, bf_, sacc, 0, 0, 0);
        }
        // C[j][i]: j = 16*wave + quad*4 + rr, i = 16*it + r16
        #pragma unroll
        for (int rr = 0; rr < 4; rr++)
            Ssum[base + (size_t)(16 * wave + quad * 4 + rr) * DK_ + 16 * it + r16] = sacc[rr];
    }
    if (tid < DK_) {
        float s = 0.0f;
        #pragma unroll
        for (int l8 = 0; l8 < 8; l8++) {
            uint4 kk = *(const uint4*)&kt[tid * 72 + l8 * 8];
            const unsigned short* kp = (const unsigned short*)&kk;
            #pragma unroll
            for (int e = 0; e < 8; e++) s += bf2f(kp[e]);
        }
        zsum[(size_t)bc * DK_ + tid] = s;
    }
}

// ---------------- K3: exclusive cross-chunk scan, 4x latency-unrolled ----------------
// 512 blocks x 256 threads; each thread owns one (bh, elem) lane of Ssum.
// Groups of 4 chunk-loads issue independently (overlapped HBM latency) before the
// serial combine — cuts exposed latency ~4x vs load->store->load chain.
__global__ __launch_bounds__(256) void k_chunk_scan(
    float* __restrict__ Ssum, float* __restrict__ zsum, const float* __restrict__ decay_log)
{
    const int tid = threadIdx.x;
    int id = blockIdx.x * 256 + tid;             // 0..131071
    int bh = id >> 12;                           // 0..31
    int elem = id & 4095;
    const int h = bh & (H_ - 1);
    const float g  = 1.0f / (1.0f + __builtin_expf(-decay_log[h]));
    const float gC = __builtin_exp2f((float)CH_ * __builtin_log2f(g));   // gamma^CH
    size_t base = (size_t)(bh * NC_) * 4096 + elem;
    float s = 0.0f;
    for (int c4 = 0; c4 < NC_; c4 += 4) {
        float v0 = Ssum[base + (size_t)(c4 + 0) * 4096];
        float v1 = Ssum[base + (size_t)(c4 + 1) * 4096];
        float v2 = Ssum[base + (size_t)(c4 + 2) * 4096];
        float v3 = Ssum[base + (size_t)(c4 + 3) * 4096];
        Ssum[base + (size_t)(c4 + 0) * 4096] = s;  s = gC * s + v0;
        Ssum[base + (size_t)(c4 + 1) * 4096] = s;  s = gC * s + v1;
        Ssum[base + (size_t)(c4 + 2) * 4096] = s;  s = gC * s + v2;
        Ssum[base + (size_t)(c4 + 3) * 4096] = s;  s = gC * s + v3;
    }
    if (id < 32 * DK_) {                          // z-scan: 2048 threads
        int zbh = id >> 6, zelem = id & 63;
        const int zh = zbh & (H_ - 1);
        const float zg  = 1.0f / (1.0f + __builtin_expf(-decay_log[zh]));
        const float zgC = __builtin_exp2f((float)CH_ * __builtin_log2f(zg));
        size_t zbase = (size_t)(zbh * NC_) * DK_ + zelem;
        float z = 0.0f;
        for (int c4 = 0; c4 < NC_; c4 += 4) {
            float v0 = zsum[zbase + (size_t)(c4 + 0) * DK_];
            float v1 = zsum[zbase + (size_t)(c4 + 1) * DK_];
            float v2 = zsum[zbase + (size_t)(c4 + 2) * DK_];
            float v3 = zsum[zbase + (size_t)(c4 + 3) * DK_];
            zsum[zbase + (size_t)(c4 + 0) * DK_] = z;  z = zgC * z + v0;
            zsum[zbase + (size_t)(c4 + 1) * DK_] = z;  z = zgC * z + v1;
            zsum[zbase + (size_t)(c4 + 2) * DK_] = z;  z = zgC * z + v2;
            zsum[zbase + (size_t)(c4 + 3) * DK_] = z;  z = zgC * z + v3;
        }
    }
}

// ---------------- K4: per-chunk outputs — QK^T, Q*S^T, PV all via MFMA ----------------
__global__ __launch_bounds__(256) void k_chunk_out(
    const unsigned short* __restrict__ Qb, const unsigned short* __restrict__ Kb,
    const unsigned short* __restrict__ Vb, const unsigned short* __restrict__ Gb,
    const float* __restrict__ Ssum, const float* __restrict__ zsum,
    unsigned short* __restrict__ OGb, const float* __restrict__ decay_log)
{
    __shared__ unsigned short ql[64 * 72];   // q rows (t,d) bf16
    __shared__ unsigned short kl[64 * 72];   // k rows (t,d) bf16
    __shared__ unsigned short sT[64 * 72];   // S_prev^T rows (j over d) bf16
    __shared__ unsigned short vt[64 * 72];   // v^T [j][l] bf16
    __shared__ unsigned short pl[64 * 72];   // P [i][l] bf16 (masked/decayed)
    __shared__ float den_l[64];
    __shared__ float zp[64];
    __shared__ float gpow[CH_ + 1];

    const int tid = threadIdx.x;
    const int bc  = blockIdx.x;
    const int c   = bc & (NC_ - 1);
    const int bh  = bc >> 5;
    const int h   = bh & (H_ - 1);
    const int b   = bh >> 3;
    const float g  = 1.0f / (1.0f + __builtin_expf(-decay_log[h]));
    const float lg = __builtin_log2f(g);
    const int t0 = c * CH_;

    if (tid <= CH_) gpow[tid] = __builtin_exp2f((float)tid * lg);
    if (tid < DK_)  zp[tid] = zsum[(size_t)bc * DK_ + tid];

    // ---- stage q,k rows (vector); v transposed (scalar scatter)
    #pragma unroll
    for (int e = 0; e < 2; e++) {
        int lid = e * 256 + tid;
        int l = lid >> 3, d0 = (lid & 7) * 8;
        size_t gidx = (size_t)(b * T_ + t0 + l) * HD_ + h * DK_ + d0;
        uint4 qraw = *(const uint4*)(Qb + gidx);
        uint4 kraw = *(const uint4*)(Kb + gidx);
        uint4 vraw = *(const uint4*)(Vb + gidx);
        *(uint4*)&ql[l * 72 + d0] = qraw;
        *(uint4*)&kl[l * 72 + d0] = kraw;
        const unsigned short* vp = (const unsigned short*)&vraw;
        #pragma unroll
        for (int j = 0; j < 8; j++) vt[(d0 + j) * 72 + l] = vp[j];
    }
    // ---- stage S_prev^T -> bf16
    {
        int j = tid >> 2, seg = tid & 3;
        const float4* src = (const float4*)&Ssum[(size_t)bc * 4096 + (size_t)j * 64 + seg * 16];
        #pragma unroll
        for (int e = 0; e < 4; e++) {
            float4 a4 = src[e];
            ushort4 o;
            o.x = f2bf(a4.x); o.y = f2bf(a4.y); o.z = f2bf(a4.z); o.w = f2bf(a4.w);
            *(ushort4*)&sT[j * 72 + seg * 16 + e * 4] = o;
        }
    }
    __syncthreads();

    const int lane = tid & 63, wave = tid >> 6;
    const int r16 = lane & 15, quad = lane >> 4;
    const int ibase = 16 * wave;

    // hoisted q fragments (reused by QK^T and carried)
    s16x8 aq[2];
    #pragma unroll
    for (int ks = 0; ks < 2; ks++)
        aq[ks] = *(const s16x8*)&ql[(ibase + r16) * 72 + ks * 32 + quad * 8];

    // ---- SC = Q K^T (MFMA): wave's i-band x all 4 l-tiles
    f32x4 sc4[4];
    #pragma unroll
    for (int lt = 0; lt < 4; lt++) {
        f32x4 s = 0.0f;
        #pragma unroll
        for (int ks = 0; ks < 2; ks++) {
            s16x8 bf_ = *(const s16x8*)&kl[(16 * lt + r16) * 72 + ks * 32 + quad * 8];
            s = __builtin_amdgcn_mfma_f32_16x16x32_bf16(aq[ks], bf_, s, 0, 0, 0);
        }
        sc4[lt] = s;
    }
    // mask + decay -> P (bf16, pl[i][l]) + intra row-sums
    float rs[4] = {0.0f, 0.0f, 0.0f, 0.0f};
    #pragma unroll
    for (int lt = 0; lt < 4; lt++) {
        int l = 16 * lt + r16;
        #pragma unroll
        for (int rr = 0; rr < 4; rr++) {
            int i = ibase + quad * 4 + rr;
            float val = (l <= i) ? sc4[lt][rr] * gpow[i - l] : 0.0f;
            unsigned short pb = f2bf(val);
            pl[i * 72 + l] = pb;
            rs[rr] += bf2f(pb);          // den consistent with rounded P
        }
    }
    #pragma unroll
    for (int rr = 0; rr < 4; rr++) {
        float v_ = rs[rr];
        v_ += __shfl_xor(v_, 1);
        v_ += __shfl_xor(v_, 2);
        v_ += __shfl_xor(v_, 4);
        v_ += __shfl_xor(v_, 8);
        if (r16 == 0) den_l[ibase + quad * 4 + rr] = v_;   // wave owns its band: no race
    }
    // ---- carried = Q * S_prev^T (MFMA), scale by gamma^(i+1)
    f32x4 og[4];
    #pragma unroll
    for (int jt = 0; jt < 4; jt++) {
        f32x4 o = 0.0f;
        #pragma unroll
        for (int ks = 0; ks < 2; ks++) {
            s16x8 bf_ = *(const s16x8*)&sT[(16 * jt + r16) * 72 + ks * 32 + quad * 8];
            o = __builtin_amdgcn_mfma_f32_16x16x32_bf16(aq[ks], bf_, o, 0, 0, 0);
        }
        #pragma unroll
        for (int rr = 0; rr < 4; rr++)
            o[rr] *= gpow[ibase + quad * 4 + rr + 1];
        og[jt] = o;
    }
    __syncthreads();   // den_l intra visible to all; pl/vt complete

    // ---- PV (MFMA): og[jt] += P * v^T — same output layout as carried
    #pragma unroll
    for (int jt = 0; jt < 4; jt++) {
        #pragma unroll
        for (int ks = 0; ks < 2; ks++) {
            s16x8 ap  = *(const s16x8*)&pl[(ibase + r16) * 72 + ks * 32 + quad * 8];
            s16x8 bf_ = *(const s16x8*)&vt[(16 * jt + r16) * 72 + ks * 32 + quad * 8];
            og[jt] = __builtin_amdgcn_mfma_f32_16x16x32_bf16(ap, bf_, og[jt], 0, 0, 0);
        }
    }
    // ---- denominator finalize: + gamma^(i+1) * q_i . z_prev + eps
    if (tid < DK_) {
        float dp = 0.0f;
        #pragma unroll
        for (int d8 = 0; d8 < 8; d8++) {
            uint4 qq = *(const uint4*)&ql[tid * 72 + d8 * 8];
            const unsigned short* qp = (const unsigned short*)&qq;
            #pragma unroll
            for (int e = 0; e < 8; e++) dp += bf2f(qp[e]) * zp[d8 * 8 + e];
        }
        den_l[tid] += gpow[tid + 1] * dp + EPS_;
    }
    __syncthreads();

    // ---- epilogue: gate * og / den -> global bf16 (i = ibase+quad*4+rr, j = 16jt+r16)
    #pragma unroll
    for (int jt = 0; jt < 4; jt++) {
        int j = 16 * jt + r16;
        #pragma unroll
        for (int rr = 0; rr < 4; rr++) {
            int i = ibase + quad * 4 + rr;
            float rcp = 1.0f / den_l[i];
            size_t ga = (size_t)(b * T_ + t0 + i) * HD_ + h * DK_ + j;
            float gate = bf2f(Gb[ga]);
            OGb[ga] = f2bf(og[jt][rr] * rcp * gate);
        }
    }
}

// ---------------- host ----------------
extern "C" void kernel_launch(void* const* d_in, const int* in_sizes, int n_in,
                              void* d_out, int out_size, void* d_ws, size_t ws_size,
                              hipStream_t stream)
{
    (void)in_sizes; (void)n_in; (void)out_size; (void)ws_size;
    const float* x         = (const float*)d_in[0];
    const float* W_Q       = (const float*)d_in[1];
    const float* W_K       = (const float*)d_in[2];
    const float* W_V       = (const float*)d_in[3];
    const float* W_gw      = (const float*)d_in[4];
    const float* W_gb      = (const float*)d_in[5];
    const float* W_O       = (const float*)d_in[6];
    const float* decay_log = (const float*)d_in[7];
    float* y = (float*)d_out;

    char* ws = (char*)d_ws;
    size_t off = 0;
    auto alloc = [&](size_t bytes) { void* p = ws + off; off += (bytes + 255) & ~(size_t)255; return p; };
    unsigned short* xb   = (unsigned short*)alloc((size_t)B_ * T_ * D_ * 2);
    unsigned short* wqb  = (unsigned short*)alloc((size_t)HD_ * D_ * 2);
    unsigned short* wkb  = (unsigned short*)alloc((size_t)HD_ * D_ * 2);
    unsigned short* wvb  = (unsigned short*)alloc((size_t)HD_ * D_ * 2);
    unsigned short* wgb  = (unsigned short*)alloc((size_t)HD_ * D_ * 2);
    unsigned short* wob  = (unsigned short*)alloc((size_t)D_ * HD_ * 2);
    unsigned short* qb   = (unsigned short*)alloc((size_t)B_ * T_ * HD_ * 2);
    unsigned short* kb   = (unsigned short*)alloc((size_t)B_ * T_ * HD_ * 2);
    unsigned short* vb   = (unsigned short*)alloc((size_t)B_ * T_ * HD_ * 2);
    unsigned short* gb   = (unsigned short*)alloc((size_t)B_ * T_ * HD_ * 2);
    unsigned short* ogb  = (unsigned short*)alloc((size_t)B_ * T_ * HD_ * 2);
    float* Ssum = (float*)alloc((size_t)B_ * H_ * NC_ * DK_ * DK_ * 4);
    float* zsum = (float*)alloc((size_t)B_ * H_ * NC_ * DK_ * 4);

    k_cvt_all<<<8192 + 5 * 512, 256, 0, stream>>>(x, W_Q, W_K, W_V, W_gw, W_O,
                                                  xb, wqb, wkb, wvb, wgb, wob);
    k_gemm_qkvg<<<256, 512, 0, stream>>>(xb, wqb, wkb, wvb, wgb, W_gb, qb, kb, vb, gb);
    k_chunk_sums<<<B_ * H_ * NC_, 256, 0, stream>>>(kb, vb, Ssum, zsum, decay_log);
    k_chunk_scan<<<512, 256, 0, stream>>>(Ssum, zsum, decay_log);
    k_chunk_out<<<B_ * H_ * NC_, 256, 0, stream>>>(qb, kb, vb, gb, Ssum, zsum, ogb, decay_log);
    k_gemm_out<<<256, 512, 0, stream>>>(ogb, wob, y);
}